// Round 2
// baseline (108.208 us; speedup 1.0000x reference)
//
#include <hip/hip_runtime.h>
#include <stdint.h>

#define NROW 1024
#define DCOL 8192
#define T1   1024
#define EPT  8                     // DCOL / T1
#define HSZ  (DCOL + (DCOL >> 6))  // 8320 words: padded histogram
#define HADDR(b) ((b) + ((b) >> 6))

// order-preserving float -> uint32 transform
__device__ __forceinline__ uint32_t sortable_key(float f){
  uint32_t u = __float_as_uint(f);
  return u ^ ((uint32_t)((int32_t)u >> 31) | 0x80000000u);
}

// Exact rank of 8192 keys held 8-per-thread across 1024 threads.
// Two-pass: 13-bit-prefix histogram -> packed (prefix<<16|count) scan ->
// refined bucket b2 = p1 + lo19*cnt>>19 (monotone, ~Poisson(1) loads) ->
// scatter (lo,idx) entries -> exact count of smaller entries in bucket.
// All integer, deterministic. h accessed through HADDR (conflict-free scans).
__device__ __forceinline__ void rank8(const uint32_t key[EPT], int t,
                                      uint32_t* h, uint32_t* ebuf,
                                      uint32_t* rk)
{
  uint32_t* wtot = ebuf;   // 16 words; dead before scatter clobbers ebuf
  __syncthreads();         // previous user of h/ebuf done
  #pragma unroll
  for (int j=0;j<EPT;j++) h[HADDR(t*EPT+j)] = 0u;
  __syncthreads();
  #pragma unroll
  for (int j=0;j<EPT;j++) atomicAdd(&h[HADDR(key[j]>>19)], 1u);
  __syncthreads();

  // scan1: h[b] := (exclusive_prefix << 16) | count   (both <= 8192)
  {
    uint32_t c[EPT]; uint32_t tot=0;
    #pragma unroll
    for (int j=0;j<EPT;j++){ c[j]=h[HADDR(t*EPT+j)]; tot+=c[j]; }
    uint32_t v=tot; int lane=t&63, wid=t>>6;
    #pragma unroll
    for (int o=1;o<64;o<<=1){ uint32_t u=__shfl_up(v,o,64); if(lane>=o) v+=u; }
    if (lane==63) wtot[wid]=v;
    __syncthreads();
    uint32_t woff=0;
    #pragma unroll
    for (int w=0;w<16;w++) woff += (w<wid) ? wtot[w] : 0u;
    uint32_t run = woff + v - tot;
    #pragma unroll
    for (int j=0;j<EPT;j++){ h[HADDR(t*EPT+j)] = (run<<16)|c[j]; run+=c[j]; }
  }
  __syncthreads();

  // refined bucket + tie-break entry
  uint32_t b2[EPT], e[EPT];
  #pragma unroll
  for (int j=0;j<EPT;j++){
    uint32_t hi = key[j]>>19, lo = key[j]&0x7FFFFu;
    uint32_t v  = h[HADDR(hi)];
    b2[j] = (v>>16) + ((lo*(v&0xFFFFu))>>19);   // lo<2^19, cnt<=2^13 -> <2^32
    e[j]  = (lo<<13) | (uint32_t)(t*EPT+j);
  }
  __syncthreads();

  // pass 2 histogram
  #pragma unroll
  for (int j=0;j<EPT;j++) h[HADDR(t*EPT+j)] = 0u;
  __syncthreads();
  #pragma unroll
  for (int j=0;j<EPT;j++) atomicAdd(&h[HADDR(b2[j])], 1u);
  __syncthreads();

  // scan2: h[b] := exclusive prefix (plain)
  {
    uint32_t c[EPT]; uint32_t tot=0;
    #pragma unroll
    for (int j=0;j<EPT;j++){ c[j]=h[HADDR(t*EPT+j)]; tot+=c[j]; }
    uint32_t v=tot; int lane=t&63, wid=t>>6;
    #pragma unroll
    for (int o=1;o<64;o<<=1){ uint32_t u=__shfl_up(v,o,64); if(lane>=o) v+=u; }
    if (lane==63) wtot[wid]=v;
    __syncthreads();
    uint32_t woff=0;
    #pragma unroll
    for (int w=0;w<16;w++) woff += (w<wid) ? wtot[w] : 0u;
    uint32_t run = woff + v - tot;
    #pragma unroll
    for (int j=0;j<EPT;j++){ h[HADDR(t*EPT+j)] = run; run+=c[j]; }
  }
  __syncthreads();

  uint32_t st[EPT];
  #pragma unroll
  for (int j=0;j<EPT;j++) st[j] = h[HADDR(b2[j])];
  __syncthreads();
  #pragma unroll
  for (int j=0;j<EPT;j++){
    uint32_t pos = atomicAdd(&h[HADDR(b2[j])], 1u);
    ebuf[pos] = e[j];
  }
  __syncthreads();
  #pragma unroll
  for (int j=0;j<EPT;j++){
    uint32_t en = h[HADDR(b2[j])];
    uint32_t cnt = 0;
    for (uint32_t p=st[j]; p<en; ++p) cnt += (ebuf[p] < e[j]) ? 1u : 0u;
    rk[j] = st[j] + cnt;
  }
}

// One block per row pair i: ranks pred[i] and eeg[i], fuses MSE partial and
// the diagonal Spearman dot. Writes both rank rows for the column-sum pass.
extern "C" __global__ void __launch_bounds__(T1)
rank_fused_kernel(const float* __restrict__ pred, const float* __restrict__ eeg,
                  uint16_t* __restrict__ ranks,
                  double* __restrict__ msepart,
                  unsigned long long* __restrict__ dotacc)
{
  __shared__ uint32_t h[HSZ];      // 33,280 B
  __shared__ uint32_t ebuf[DCOL];  // 32,768 B
  __shared__ double   redd[16];
  __shared__ unsigned long long redu[16];

  const int t = threadIdx.x, bid = blockIdx.x;
  const float4* p4 = (const float4*)(pred + (size_t)bid*DCOL + t*EPT);
  const float4* e4 = (const float4*)(eeg  + (size_t)bid*DCOL + t*EPT);
  float4 pa = p4[0], pb = p4[1], ea = e4[0], eb = e4[1];

  // fused MSE partial (same formula as validated round-1 kernel)
  float d0,d1,d2,d3;
  double msum = 0.0;
  d0=pa.x-ea.x; d1=pa.y-ea.y; d2=pa.z-ea.z; d3=pa.w-ea.w;
  msum += (double)(d0*d0)+(double)(d1*d1)+(double)(d2*d2)+(double)(d3*d3);
  d0=pb.x-eb.x; d1=pb.y-eb.y; d2=pb.z-eb.z; d3=pb.w-eb.w;
  msum += (double)(d0*d0)+(double)(d1*d1)+(double)(d2*d2)+(double)(d3*d3);

  uint32_t kp[EPT], ke[EPT];
  kp[0]=sortable_key(pa.x); kp[1]=sortable_key(pa.y);
  kp[2]=sortable_key(pa.z); kp[3]=sortable_key(pa.w);
  kp[4]=sortable_key(pb.x); kp[5]=sortable_key(pb.y);
  kp[6]=sortable_key(pb.z); kp[7]=sortable_key(pb.w);
  ke[0]=sortable_key(ea.x); ke[1]=sortable_key(ea.y);
  ke[2]=sortable_key(ea.z); ke[3]=sortable_key(ea.w);
  ke[4]=sortable_key(eb.x); ke[5]=sortable_key(eb.y);
  ke[6]=sortable_key(eb.z); ke[7]=sortable_key(eb.w);

  uint32_t ra[EPT];
  rank8(kp, t, h, ebuf, ra);

  // pack + write pred ranks now; keep only 4 packed regs live through rank2
  uint4 packa;
  packa.x = ra[0] | (ra[1]<<16);
  packa.y = ra[2] | (ra[3]<<16);
  packa.z = ra[4] | (ra[5]<<16);
  packa.w = ra[6] | (ra[7]<<16);
  *(uint4*)(ranks + (size_t)bid*DCOL + (size_t)t*EPT) = packa;

  uint32_t rb[EPT];
  rank8(ke, t, h, ebuf, rb);
  uint4 packb;
  packb.x = rb[0] | (rb[1]<<16);
  packb.y = rb[2] | (rb[3]<<16);
  packb.z = rb[4] | (rb[5]<<16);
  packb.w = rb[6] | (rb[7]<<16);
  *(uint4*)(ranks + (size_t)(NROW+bid)*DCOL + (size_t)t*EPT) = packb;

  // diagonal dot: sum rank_a * rank_b (exact, fits u32 per thread)
  uint32_t dp = 0;
  dp += (packa.x&0xFFFFu)*(packb.x&0xFFFFu) + (packa.x>>16)*(packb.x>>16);
  dp += (packa.y&0xFFFFu)*(packb.y&0xFFFFu) + (packa.y>>16)*(packb.y>>16);
  dp += (packa.z&0xFFFFu)*(packb.z&0xFFFFu) + (packa.z>>16)*(packb.z>>16);
  dp += (packa.w&0xFFFFu)*(packb.w&0xFFFFu) + (packa.w>>16)*(packb.w>>16);

  unsigned long long dpl = dp;
  for (int o=32;o>0;o>>=1){ msum += __shfl_down(msum,o,64); dpl += __shfl_down(dpl,o,64); }
  int lane=t&63, wid=t>>6;
  __syncthreads();                       // counting loop reads done (redd/redu separate anyway)
  if (lane==0){ redd[wid]=msum; redu[wid]=dpl; }
  __syncthreads();
  if (t==0){
    double ms=0.0; unsigned long long dl=0ull;
    #pragma unroll
    for (int w=0;w<16;w++){ ms+=redd[w]; dl+=redu[w]; }
    msepart[bid] = ms;
    atomicAdd(dotacc, dl);
  }
}

// Column sums of rank matrices (exact u32). Reads 32 MB once.
extern "C" __global__ void __launch_bounds__(256)
colsum_kernel(const uint16_t* __restrict__ ranks,
              uint32_t* __restrict__ SA, uint32_t* __restrict__ SB)
{
  const int t = threadIdx.x;
  const int col = blockIdx.x*1024 + t*4;
  const int r0  = blockIdx.y*32;
  const uint16_t* rp = ranks;
  const uint16_t* re = ranks + (size_t)NROW*DCOL;
  uint32_t sa0=0,sa1=0,sa2=0,sa3=0, sb0=0,sb1=0,sb2=0,sb3=0;
  for (int i=0;i<32;i++){
    uint2 va = *(const uint2*)&rp[(size_t)(r0+i)*DCOL + col];
    uint2 vb = *(const uint2*)&re[(size_t)(r0+i)*DCOL + col];
    sa0 += va.x&0xFFFFu; sa1 += va.x>>16; sa2 += va.y&0xFFFFu; sa3 += va.y>>16;
    sb0 += vb.x&0xFFFFu; sb1 += vb.x>>16; sb2 += vb.y&0xFFFFu; sb3 += vb.y>>16;
  }
  atomicAdd(&SA[col+0],sa0); atomicAdd(&SA[col+1],sa1);
  atomicAdd(&SA[col+2],sa2); atomicAdd(&SA[col+3],sa3);
  atomicAdd(&SB[col+0],sb0); atomicAdd(&SB[col+1],sb1);
  atomicAdd(&SB[col+2],sb2); atomicAdd(&SB[col+3],sb3);
}

extern "C" __global__ void __launch_bounds__(256)
final_kernel(const uint32_t* __restrict__ SA, const uint32_t* __restrict__ SB,
             const unsigned long long* __restrict__ dotacc,
             const double* __restrict__ msepart, int nmse,
             float* __restrict__ out)
{
  __shared__ double wpartd[4];
  __shared__ double wpartm[4];
  const int t = threadIdx.x;
  const double NMU = 4193792.0;    // N * mu, mu = (D-1)/2 = 4095.5
  double s = 0.0;
  for (int i=0;i<DCOL/256;i++){
    int k = i*256+t;
    s += ((double)SA[k]-NMU)*((double)SB[k]-NMU);
  }
  double m = 0.0;
  for (int i=t; i<nmse; i+=256) m += msepart[i];
  for (int o=32;o>0;o>>=1){ s+=__shfl_down(s,o,64); m+=__shfl_down(m,o,64); }
  int lane=t&63, wid=t>>6;
  if (lane==0){ wpartd[wid]=s; wpartm[wid]=m; }
  __syncthreads();
  if (t==0){
    double sasb   = wpartd[0]+wpartd[1]+wpartd[2]+wpartd[3];
    double msesum = wpartm[0]+wpartm[1]+wpartm[2]+wpartm[3];
    const double C     = 45812983808.0;        // D*(D^2-1)/12
    const double NDMU2 = 140703130714112.0;    // N * D * mu^2
    double dot = (double)(*dotacc);
    double diag_sum = (dot - NDMU2) / C;       // sum_i corr_ii
    double pos = diag_sum / (double)NROW;
    double stotal = sasb / C;                  // sum_ij corr_ij
    double neg = (stotal - diag_sum) / ((double)NROW*(double)(NROW-1));
    double loss1 = msesum / ((double)NROW*(double)DCOL);
    out[0] = (float)(loss1 + 1.0 - pos + neg);
  }
}

extern "C" void kernel_launch(void* const* d_in, const int* in_sizes, int n_in,
                              void* d_out, int out_size, void* d_ws, size_t ws_size,
                              hipStream_t stream)
{
  const float* pred = (const float*)d_in[0];
  const float* eeg  = (const float*)d_in[1];
  float* out = (float*)d_out;

  char* ws = (char*)d_ws;
  const size_t OFF_ACC = (size_t)2*NROW*DCOL*sizeof(uint16_t);   // 33,554,432
  const size_t NEED = OFF_ACC + 65536 + 64 + NROW*sizeof(double);
  if (ws_size < NEED){
    hipMemsetAsync(d_out, 0xFF, sizeof(float), stream);
    return;
  }
  uint16_t* ranks = (uint16_t*)ws;
  uint32_t* SA = (uint32_t*)(ws + OFF_ACC);
  uint32_t* SB = (uint32_t*)(ws + OFF_ACC + 32768);
  unsigned long long* dotacc = (unsigned long long*)(ws + OFF_ACC + 65536);
  double* msepart = (double*)(ws + OFF_ACC + 65536 + 64);

  hipMemsetAsync(ws + OFF_ACC, 0, 65536 + 64, stream);   // zero SA, SB, dotacc

  rank_fused_kernel<<<dim3(NROW), dim3(T1), 0, stream>>>(pred, eeg, ranks, msepart, dotacc);
  colsum_kernel<<<dim3(8, 32), dim3(256), 0, stream>>>(ranks, SA, SB);
  final_kernel<<<dim3(1), dim3(256), 0, stream>>>(SA, SB, dotacc, msepart, NROW, out);
}

// Round 3
// 104.885 us; speedup vs baseline: 1.0317x; 1.0317x over previous
//
#include <hip/hip_runtime.h>
#include <stdint.h>

#define NROW 1024
#define DCOL 8192
#define T1   1024
#define EPT  8

// order-preserving float -> uint32 transform
__device__ __forceinline__ uint32_t sortable_key(float f){
  uint32_t u = __float_as_uint(f);
  return u ^ ((uint32_t)((int32_t)u >> 31) | 0x80000000u);
}

// One block ranks one row. Two-level counting rank, all-integer, exact,
// deterministic. h: hist1/packed-prefix1, then entry buffer. g: hist2/cursor.
// eeg blocks (r >= NROW) also stream the matching pred row for the MSE partial.
extern "C" __global__ void __launch_bounds__(T1)
rank_kernel(const float* __restrict__ pred, const float* __restrict__ eeg,
            uint16_t* __restrict__ ranks, double* __restrict__ msepart)
{
  __shared__ uint32_t h[DCOL];     // 32 KB
  __shared__ uint32_t g[DCOL];     // 32 KB
  __shared__ uint32_t wt[16];
  __shared__ double   redd[16];

  const int t = threadIdx.x, r = blockIdx.x;
  const int lane = t & 63, wid = t >> 6;
  const bool is_eeg = (r >= NROW);
  const float* src = is_eeg ? (eeg + (size_t)(r - NROW) * DCOL)
                            : (pred + (size_t)r * DCOL);

  const float4* s4 = (const float4*)(src + t * EPT);
  float4 va = s4[0], vb = s4[1];

  // zero both LDS tables with b128 stores; overlaps with key/MSE computation
  {
    uint4 z = make_uint4(0u,0u,0u,0u);
    *(uint4*)&h[t*EPT]   = z;
    *(uint4*)&h[t*EPT+4] = z;
    *(uint4*)&g[t*EPT]   = z;
    *(uint4*)&g[t*EPT+4] = z;
  }

  double msum = 0.0;
  if (is_eeg){
    const float4* p4 = (const float4*)(pred + (size_t)(r - NROW) * DCOL + t * EPT);
    float4 qa = p4[0], qb = p4[1];
    float d;
    d=qa.x-va.x; msum += (double)(d*d);
    d=qa.y-va.y; msum += (double)(d*d);
    d=qa.z-va.z; msum += (double)(d*d);
    d=qa.w-va.w; msum += (double)(d*d);
    d=qb.x-vb.x; msum += (double)(d*d);
    d=qb.y-vb.y; msum += (double)(d*d);
    d=qb.z-vb.z; msum += (double)(d*d);
    d=qb.w-vb.w; msum += (double)(d*d);
  }

  uint32_t key[EPT];
  key[0]=sortable_key(va.x); key[1]=sortable_key(va.y);
  key[2]=sortable_key(va.z); key[3]=sortable_key(va.w);
  key[4]=sortable_key(vb.x); key[5]=sortable_key(vb.y);
  key[6]=sortable_key(vb.z); key[7]=sortable_key(vb.w);
  __syncthreads();                               // (1) zeros visible

  // pass 1: histogram of top-13 bits
  #pragma unroll
  for (int j=0;j<EPT;j++) atomicAdd(&h[key[j]>>19], 1u);
  __syncthreads();                               // (2)

  // scan1: h[b] := (exclusive_prefix << 16) | count
  {
    uint4 ca = *(const uint4*)&h[t*EPT];
    uint4 cb = *(const uint4*)&h[t*EPT+4];
    uint32_t tot = ca.x+ca.y+ca.z+ca.w+cb.x+cb.y+cb.z+cb.w;
    uint32_t v = tot;
    #pragma unroll
    for (int o=1;o<64;o<<=1){ uint32_t u=__shfl_up(v,o,64); if(lane>=o) v+=u; }
    if (lane==63) wt[wid]=v;
    __syncthreads();                             // (3)
    uint32_t run = v - tot;
    #pragma unroll
    for (int w=0;w<16;w++) run += (w<wid)? wt[w] : 0u;
    uint4 oa, ob;
    oa.x=(run<<16)|ca.x; run+=ca.x;
    oa.y=(run<<16)|ca.y; run+=ca.y;
    oa.z=(run<<16)|ca.z; run+=ca.z;
    oa.w=(run<<16)|ca.w; run+=ca.w;
    ob.x=(run<<16)|cb.x; run+=cb.x;
    ob.y=(run<<16)|cb.y; run+=cb.y;
    ob.z=(run<<16)|cb.z; run+=cb.z;
    ob.w=(run<<16)|cb.w; run+=cb.w;
    *(uint4*)&h[t*EPT]   = oa;
    *(uint4*)&h[t*EPT+4] = ob;
  }
  __syncthreads();                               // (4)

  // refine: b2 = p1 + lo19*cnt>>19 (monotone, disjoint per coarse bucket)
  // + pass-2 histogram directly into g (zeroed at start, untouched since)
  uint32_t b2[EPT], e[EPT];
  #pragma unroll
  for (int j=0;j<EPT;j++){
    uint32_t hi = key[j]>>19, lo = key[j]&0x7FFFFu;
    uint32_t v  = h[hi];
    b2[j] = (v>>16) + ((lo*(v&0xFFFFu))>>19);    // lo<2^19, cnt<=2^13 -> <2^32
    e[j]  = (lo<<13) | (uint32_t)(t*EPT+j);
    atomicAdd(&g[b2[j]], 1u);
  }
  __syncthreads();                               // (5)

  // scan2: g[b] := (start<<16) | start   (low half doubles as scatter cursor)
  {
    uint4 ca = *(const uint4*)&g[t*EPT];
    uint4 cb = *(const uint4*)&g[t*EPT+4];
    uint32_t tot = ca.x+ca.y+ca.z+ca.w+cb.x+cb.y+cb.z+cb.w;
    uint32_t v = tot;
    #pragma unroll
    for (int o=1;o<64;o<<=1){ uint32_t u=__shfl_up(v,o,64); if(lane>=o) v+=u; }
    if (lane==63) wt[wid]=v;
    __syncthreads();                             // (6)
    uint32_t run = v - tot;
    #pragma unroll
    for (int w=0;w<16;w++) run += (w<wid)? wt[w] : 0u;
    uint4 oa, ob;
    oa.x=(run<<16)|run; run+=ca.x;
    oa.y=(run<<16)|run; run+=ca.y;
    oa.z=(run<<16)|run; run+=ca.z;
    oa.w=(run<<16)|run; run+=ca.w;
    ob.x=(run<<16)|run; run+=cb.x;
    ob.y=(run<<16)|run; run+=cb.y;
    ob.z=(run<<16)|run; run+=cb.z;
    ob.w=(run<<16)|run; run+=cb.w;
    *(uint4*)&g[t*EPT]   = oa;
    *(uint4*)&g[t*EPT+4] = ob;
  }
  __syncthreads();                               // (7)

  // scatter into h (h is dead after refine): one atomic yields start AND pos
  uint32_t old[EPT];
  #pragma unroll
  for (int j=0;j<EPT;j++){
    old[j] = atomicAdd(&g[b2[j]], 1u);           // hi16=start, lo16=pos cursor
    h[old[j] & 0xFFFFu] = e[j];
  }
  __syncthreads();                               // (8)

  // exact rank = start + #(smaller entries in refined bucket)
  uint32_t rk[EPT];
  #pragma unroll
  for (int j=0;j<EPT;j++){
    uint32_t st = old[j] >> 16;
    uint32_t en = g[b2[j]] & 0xFFFFu;            // cursor now == bucket end
    uint32_t cnt = 0;
    for (uint32_t p = st; p < en; ++p) cnt += (h[p] < e[j]) ? 1u : 0u;
    rk[j] = st + cnt;
  }

  uint4 pk;
  pk.x = rk[0] | (rk[1]<<16);
  pk.y = rk[2] | (rk[3]<<16);
  pk.z = rk[4] | (rk[5]<<16);
  pk.w = rk[6] | (rk[7]<<16);
  *(uint4*)(ranks + (size_t)r*DCOL + (size_t)t*EPT) = pk;

  if (is_eeg){
    #pragma unroll
    for (int o=32;o>0;o>>=1) msum += __shfl_down(msum,o,64);
    if (lane==0) redd[wid]=msum;
    __syncthreads();
    if (t==0){
      double m=0.0;
      #pragma unroll
      for (int w=0;w<16;w++) m += redd[w];
      msepart[r-NROW]=m;
    }
  }
}

// Column sums (SA|SB packed in u64, exact; no overflow: col sum <= 8.4M) and
// diagonal Spearman dot (exact u64), fused over one 32 MB read of the ranks.
extern "C" __global__ void __launch_bounds__(256)
colsum_kernel(const uint16_t* __restrict__ ranks,
              unsigned long long* __restrict__ SAB,
              unsigned long long* __restrict__ dotacc)
{
  const int t = threadIdx.x;
  const int col = blockIdx.x*2048 + t*8;
  const int r0  = blockIdx.y*16;
  const uint16_t* rp = ranks;
  const uint16_t* re = ranks + (size_t)NROW*DCOL;
  uint32_t sa[8] = {0,0,0,0,0,0,0,0};
  uint32_t sb[8] = {0,0,0,0,0,0,0,0};
  unsigned long long dt = 0ull;
  for (int i=0;i<16;i++){
    uint4 a = *(const uint4*)&rp[(size_t)(r0+i)*DCOL + col];
    uint4 b = *(const uint4*)&re[(size_t)(r0+i)*DCOL + col];
    uint32_t aw[8] = {a.x&0xFFFFu,a.x>>16,a.y&0xFFFFu,a.y>>16,
                      a.z&0xFFFFu,a.z>>16,a.w&0xFFFFu,a.w>>16};
    uint32_t bw[8] = {b.x&0xFFFFu,b.x>>16,b.y&0xFFFFu,b.y>>16,
                      b.z&0xFFFFu,b.z>>16,b.w&0xFFFFu,b.w>>16};
    uint32_t rowdt = 0;
    #pragma unroll
    for (int k=0;k<8;k++){ sa[k]+=aw[k]; sb[k]+=bw[k]; rowdt += aw[k]*bw[k]; }
    dt += (unsigned long long)rowdt;             // rowdt <= 8*8191^2 < 2^32
  }
  #pragma unroll
  for (int k=0;k<8;k++)
    atomicAdd(&SAB[col+k], (unsigned long long)sa[k]
                           | ((unsigned long long)sb[k]<<32));
  #pragma unroll
  for (int o=32;o>0;o>>=1) dt += __shfl_down(dt,o,64);
  if ((t&63)==0) atomicAdd(dotacc, dt);
}

extern "C" __global__ void __launch_bounds__(256)
final_kernel(const unsigned long long* __restrict__ SAB,
             const unsigned long long* __restrict__ dotacc,
             const double* __restrict__ msepart,
             float* __restrict__ out)
{
  __shared__ double wpartd[4], wpartm[4];
  const int t = threadIdx.x;
  const double NMU = 4193792.0;                  // N * mu, mu = (D-1)/2
  double s = 0.0;
  for (int i=0;i<DCOL/256;i++){
    unsigned long long v = SAB[i*256+t];
    double sa = (double)(uint32_t)v;
    double sb = (double)(uint32_t)(v>>32);
    s += (sa-NMU)*(sb-NMU);
  }
  double m = 0.0;
  for (int i=t;i<NROW;i+=256) m += msepart[i];
  #pragma unroll
  for (int o=32;o>0;o>>=1){ s+=__shfl_down(s,o,64); m+=__shfl_down(m,o,64); }
  int lane=t&63, wid=t>>6;
  if (lane==0){ wpartd[wid]=s; wpartm[wid]=m; }
  __syncthreads();
  if (t==0){
    double sasb   = wpartd[0]+wpartd[1]+wpartd[2]+wpartd[3];
    double msesum = wpartm[0]+wpartm[1]+wpartm[2]+wpartm[3];
    const double C     = 45812983808.0;          // D*(D^2-1)/12
    const double NDMU2 = 140703130714112.0;      // N * D * mu^2
    double dot = (double)(*dotacc);
    double diag_sum = (dot - NDMU2) / C;         // sum_i corr_ii
    double pos = diag_sum / (double)NROW;
    double stotal = sasb / C;                    // sum_ij corr_ij
    double neg = (stotal - diag_sum) / ((double)NROW*(double)(NROW-1));
    double loss1 = msesum / ((double)NROW*(double)DCOL);
    out[0] = (float)(loss1 + 1.0 - pos + neg);
  }
}

extern "C" void kernel_launch(void* const* d_in, const int* in_sizes, int n_in,
                              void* d_out, int out_size, void* d_ws, size_t ws_size,
                              hipStream_t stream)
{
  const float* pred = (const float*)d_in[0];
  const float* eeg  = (const float*)d_in[1];
  float* out = (float*)d_out;

  char* ws = (char*)d_ws;
  const size_t OFF = (size_t)2*NROW*DCOL*sizeof(uint16_t);   // 33,554,432
  const size_t NEED = OFF + 65536 + 8 + (size_t)NROW*sizeof(double);
  if (ws_size < NEED){
    hipMemsetAsync(d_out, 0xFF, sizeof(float), stream);      // signal: ws too small
    return;
  }
  uint16_t* ranks = (uint16_t*)ws;
  unsigned long long* SAB    = (unsigned long long*)(ws + OFF);
  unsigned long long* dotacc = (unsigned long long*)(ws + OFF + 65536);
  double* msepart            = (double*)(ws + OFF + 65536 + 8);

  hipMemsetAsync(ws + OFF, 0, 65536 + 8, stream);            // zero SAB + dotacc

  rank_kernel<<<dim3(2*NROW), dim3(T1), 0, stream>>>(pred, eeg, ranks, msepart);
  colsum_kernel<<<dim3(4,64), dim3(256), 0, stream>>>(ranks, SAB, dotacc);
  final_kernel<<<dim3(1), dim3(256), 0, stream>>>(SAB, dotacc, msepart, out);
}

// Round 4
// 79.371 us; speedup vs baseline: 1.3633x; 1.3215x over previous
//
#include <hip/hip_runtime.h>
#include <stdint.h>

#define NROW 1024
#define DCOL 8192
#define T1   1024
#define EPT  8

typedef unsigned long long u64;

// order-preserving float -> uint32 transform
__device__ __forceinline__ uint32_t sortable_key(float f){
  uint32_t u = __float_as_uint(f);
  return u ^ ((uint32_t)((int32_t)u >> 31) | 0x80000000u);
}

// One block ranks one row. Two-level counting rank, all-integer, exact,
// deterministic. Blocks interleave pred/eeg (bid even=pred, odd=eeg) for
// dispatch balance; eeg blocks also stream the matching pred row (L2-hot,
// just fetched by block bid-1) for the fused MSE partial.
extern "C" __global__ void __launch_bounds__(T1)
rank_kernel(const float* __restrict__ pred, const float* __restrict__ eeg,
            uint16_t* __restrict__ ranks, double* __restrict__ msepart)
{
  __shared__ uint32_t h[DCOL];     // 32 KB
  __shared__ uint32_t g[DCOL];     // 32 KB
  __shared__ uint32_t wt[16];
  __shared__ double   redd[16];

  const int t = threadIdx.x;
  const int pair = blockIdx.x >> 1;
  const bool is_eeg = blockIdx.x & 1;
  const int lane = t & 63, wid = t >> 6;
  const float* src = is_eeg ? (eeg  + (size_t)pair * DCOL)
                            : (pred + (size_t)pair * DCOL);

  const float4* s4 = (const float4*)(src + t * EPT);
  float4 va = s4[0], vb = s4[1];

  // zero both LDS tables with b128 stores; overlaps with key/MSE computation
  {
    uint4 z = make_uint4(0u,0u,0u,0u);
    *(uint4*)&h[t*EPT]   = z;
    *(uint4*)&h[t*EPT+4] = z;
    *(uint4*)&g[t*EPT]   = z;
    *(uint4*)&g[t*EPT+4] = z;
  }

  double msum = 0.0;
  if (is_eeg){
    const float4* p4 = (const float4*)(pred + (size_t)pair * DCOL + t * EPT);
    float4 qa = p4[0], qb = p4[1];
    float d;
    d=qa.x-va.x; msum += (double)(d*d);
    d=qa.y-va.y; msum += (double)(d*d);
    d=qa.z-va.z; msum += (double)(d*d);
    d=qa.w-va.w; msum += (double)(d*d);
    d=qb.x-vb.x; msum += (double)(d*d);
    d=qb.y-vb.y; msum += (double)(d*d);
    d=qb.z-vb.z; msum += (double)(d*d);
    d=qb.w-vb.w; msum += (double)(d*d);
  }

  uint32_t key[EPT];
  key[0]=sortable_key(va.x); key[1]=sortable_key(va.y);
  key[2]=sortable_key(va.z); key[3]=sortable_key(va.w);
  key[4]=sortable_key(vb.x); key[5]=sortable_key(vb.y);
  key[6]=sortable_key(vb.z); key[7]=sortable_key(vb.w);
  __syncthreads();                               // (1) zeros visible

  // pass 1: histogram of top-13 bits
  #pragma unroll
  for (int j=0;j<EPT;j++) atomicAdd(&h[key[j]>>19], 1u);
  __syncthreads();                               // (2)

  // scan1: h[b] := (exclusive_prefix << 16) | count
  {
    uint4 ca = *(const uint4*)&h[t*EPT];
    uint4 cb = *(const uint4*)&h[t*EPT+4];
    uint32_t tot = ca.x+ca.y+ca.z+ca.w+cb.x+cb.y+cb.z+cb.w;
    uint32_t v = tot;
    #pragma unroll
    for (int o=1;o<64;o<<=1){ uint32_t u=__shfl_up(v,o,64); if(lane>=o) v+=u; }
    if (lane==63) wt[wid]=v;
    __syncthreads();                             // (3)
    uint32_t run = v - tot;
    #pragma unroll
    for (int w=0;w<16;w++) run += (w<wid)? wt[w] : 0u;
    uint4 oa, ob;
    oa.x=(run<<16)|ca.x; run+=ca.x;
    oa.y=(run<<16)|ca.y; run+=ca.y;
    oa.z=(run<<16)|ca.z; run+=ca.z;
    oa.w=(run<<16)|ca.w; run+=ca.w;
    ob.x=(run<<16)|cb.x; run+=cb.x;
    ob.y=(run<<16)|cb.y; run+=cb.y;
    ob.z=(run<<16)|cb.z; run+=cb.z;
    ob.w=(run<<16)|cb.w; run+=cb.w;
    *(uint4*)&h[t*EPT]   = oa;
    *(uint4*)&h[t*EPT+4] = ob;
  }
  __syncthreads();                               // (4)

  // refine: b2 = p1 + lo19*cnt>>19 (monotone, disjoint per coarse bucket)
  // + pass-2 histogram directly into g
  uint32_t b2[EPT], e[EPT];
  #pragma unroll
  for (int j=0;j<EPT;j++){
    uint32_t hi = key[j]>>19, lo = key[j]&0x7FFFFu;
    uint32_t v  = h[hi];
    b2[j] = (v>>16) + ((lo*(v&0xFFFFu))>>19);    // lo<2^19, cnt<=2^13 -> <2^32
    e[j]  = (lo<<13) | (uint32_t)(t*EPT+j);
    atomicAdd(&g[b2[j]], 1u);
  }
  __syncthreads();                               // (5)

  // scan2: g[b] := (start<<16) | start   (low half doubles as scatter cursor)
  {
    uint4 ca = *(const uint4*)&g[t*EPT];
    uint4 cb = *(const uint4*)&g[t*EPT+4];
    uint32_t tot = ca.x+ca.y+ca.z+ca.w+cb.x+cb.y+cb.z+cb.w;
    uint32_t v = tot;
    #pragma unroll
    for (int o=1;o<64;o<<=1){ uint32_t u=__shfl_up(v,o,64); if(lane>=o) v+=u; }
    if (lane==63) wt[wid]=v;
    __syncthreads();                             // (6)
    uint32_t run = v - tot;
    #pragma unroll
    for (int w=0;w<16;w++) run += (w<wid)? wt[w] : 0u;
    uint4 oa, ob;
    oa.x=(run<<16)|run; run+=ca.x;
    oa.y=(run<<16)|run; run+=ca.y;
    oa.z=(run<<16)|run; run+=ca.z;
    oa.w=(run<<16)|run; run+=ca.w;
    ob.x=(run<<16)|run; run+=cb.x;
    ob.y=(run<<16)|run; run+=cb.y;
    ob.z=(run<<16)|run; run+=cb.z;
    ob.w=(run<<16)|run; run+=cb.w;
    *(uint4*)&g[t*EPT]   = oa;
    *(uint4*)&g[t*EPT+4] = ob;
  }
  __syncthreads();                               // (7)

  // scatter into h (h is dead after refine): one atomic yields start AND pos
  uint32_t old[EPT];
  #pragma unroll
  for (int j=0;j<EPT;j++){
    old[j] = atomicAdd(&g[b2[j]], 1u);           // hi16=start, lo16=pos cursor
    h[old[j] & 0xFFFFu] = e[j];
  }
  __syncthreads();                               // (8)

  // exact rank = start + #(smaller entries in refined bucket)
  uint32_t rk[EPT];
  #pragma unroll
  for (int j=0;j<EPT;j++){
    uint32_t st = old[j] >> 16;
    uint32_t en = g[b2[j]] & 0xFFFFu;            // cursor now == bucket end
    uint32_t cnt = 0;
    for (uint32_t p = st; p < en; ++p) cnt += (h[p] < e[j]) ? 1u : 0u;
    rk[j] = st + cnt;
  }

  uint4 pk;
  pk.x = rk[0] | (rk[1]<<16);
  pk.y = rk[2] | (rk[3]<<16);
  pk.z = rk[4] | (rk[5]<<16);
  pk.w = rk[6] | (rk[7]<<16);
  const size_t orow = is_eeg ? (size_t)(NROW + pair) : (size_t)pair;
  *(uint4*)(ranks + orow*DCOL + (size_t)t*EPT) = pk;

  if (is_eeg){
    #pragma unroll
    for (int o=32;o>0;o>>=1) msum += __shfl_down(msum,o,64);
    if (lane==0) redd[wid]=msum;
    __syncthreads();
    if (t==0){
      double m=0.0;
      #pragma unroll
      for (int w=0;w<16;w++) m += redd[w];
      msepart[pair]=m;
    }
  }
}

// ---------- atomic-free back end (primary path) ----------
// Each (bx,by) block: 16 rows x 2048 cols -> private partial slice + dot part.
extern "C" __global__ void __launch_bounds__(256)
colsum_part_kernel(const uint16_t* __restrict__ ranks,
                   u64* __restrict__ SABpart, u64* __restrict__ dotpart)
{
  __shared__ u64 redu[4];
  const int t = threadIdx.x;
  const int bx = blockIdx.x, by = blockIdx.y;
  const int col = bx*2048 + t*8;
  const int r0  = by*16;
  const uint16_t* rp = ranks;
  const uint16_t* re = ranks + (size_t)NROW*DCOL;
  uint32_t sa[8] = {0,0,0,0,0,0,0,0};
  uint32_t sb[8] = {0,0,0,0,0,0,0,0};
  u64 dt = 0ull;
  #pragma unroll
  for (int i=0;i<16;i++){
    uint4 a = *(const uint4*)&rp[(size_t)(r0+i)*DCOL + col];
    uint4 b = *(const uint4*)&re[(size_t)(r0+i)*DCOL + col];
    uint32_t aw[8] = {a.x&0xFFFFu,a.x>>16,a.y&0xFFFFu,a.y>>16,
                      a.z&0xFFFFu,a.z>>16,a.w&0xFFFFu,a.w>>16};
    uint32_t bw[8] = {b.x&0xFFFFu,b.x>>16,b.y&0xFFFFu,b.y>>16,
                      b.z&0xFFFFu,b.z>>16,b.w&0xFFFFu,b.w>>16};
    uint32_t rowdt = 0;
    #pragma unroll
    for (int k=0;k<8;k++){ sa[k]+=aw[k]; sb[k]+=bw[k]; rowdt += aw[k]*bw[k]; }
    dt += (u64)rowdt;                            // rowdt <= 8*8191^2 < 2^32
  }
  u64* dst = SABpart + (size_t)by*DCOL + col;
  #pragma unroll
  for (int k=0;k<8;k++) dst[k] = (u64)sa[k] | ((u64)sb[k]<<32);

  #pragma unroll
  for (int o=32;o>0;o>>=1) dt += __shfl_down(dt,o,64);
  int lane=t&63, wid=t>>6;
  if (lane==0) redu[wid]=dt;
  __syncthreads();
  if (t==0) dotpart[by*4+bx] = redu[0]+redu[1]+redu[2]+redu[3];
}

extern "C" __global__ void __launch_bounds__(128)
reduce_kernel(const u64* __restrict__ SABpart, u64* __restrict__ SAB)
{
  const int col = blockIdx.x*128 + threadIdx.x;
  u64 s = 0ull;
  #pragma unroll
  for (int by=0; by<64; by++) s += SABpart[(size_t)by*DCOL + col];
  SAB[col] = s;   // low32 = SA (<= 8.4M), high32 = SB: no cross-carry
}

extern "C" __global__ void __launch_bounds__(256)
final_part_kernel(const u64* __restrict__ SAB, const u64* __restrict__ dotpart,
                  const double* __restrict__ msepart, float* __restrict__ out)
{
  __shared__ double wpartd[4], wpartm[4];
  __shared__ u64 wpartu[4];
  const int t = threadIdx.x;
  const double NMU = 4193792.0;                  // N * mu, mu = (D-1)/2
  double s = 0.0;
  for (int i=0;i<DCOL/256;i++){
    u64 v = SAB[i*256+t];
    s += ((double)(uint32_t)v - NMU)*((double)(uint32_t)(v>>32) - NMU);
  }
  double m = 0.0;
  for (int i=t;i<NROW;i+=256) m += msepart[i];
  u64 d = dotpart[t];
  #pragma unroll
  for (int o=32;o>0;o>>=1){
    s+=__shfl_down(s,o,64); m+=__shfl_down(m,o,64); d+=__shfl_down(d,o,64);
  }
  int lane=t&63, wid=t>>6;
  if (lane==0){ wpartd[wid]=s; wpartm[wid]=m; wpartu[wid]=d; }
  __syncthreads();
  if (t==0){
    double sasb   = wpartd[0]+wpartd[1]+wpartd[2]+wpartd[3];
    double msesum = wpartm[0]+wpartm[1]+wpartm[2]+wpartm[3];
    double dot    = (double)(wpartu[0]+wpartu[1]+wpartu[2]+wpartu[3]);
    const double C     = 45812983808.0;          // D*(D^2-1)/12
    const double NDMU2 = 140703130714112.0;      // N * D * mu^2
    double diag_sum = (dot - NDMU2) / C;         // sum_i corr_ii
    double pos = diag_sum / (double)NROW;
    double stotal = sasb / C;                    // sum_ij corr_ij
    double neg = (stotal - diag_sum) / ((double)NROW*(double)(NROW-1));
    double loss1 = msesum / ((double)NROW*(double)DCOL);
    out[0] = (float)(loss1 + 1.0 - pos + neg);
  }
}

// ---------- atomic fallback (only if ws too small for partials) ----------
extern "C" __global__ void __launch_bounds__(256)
colsum_atomic_kernel(const uint16_t* __restrict__ ranks,
                     u64* __restrict__ SAB, u64* __restrict__ dotacc)
{
  const int t = threadIdx.x;
  const int col = blockIdx.x*2048 + t*8;
  const int r0  = blockIdx.y*16;
  const uint16_t* rp = ranks;
  const uint16_t* re = ranks + (size_t)NROW*DCOL;
  uint32_t sa[8] = {0,0,0,0,0,0,0,0};
  uint32_t sb[8] = {0,0,0,0,0,0,0,0};
  u64 dt = 0ull;
  for (int i=0;i<16;i++){
    uint4 a = *(const uint4*)&rp[(size_t)(r0+i)*DCOL + col];
    uint4 b = *(const uint4*)&re[(size_t)(r0+i)*DCOL + col];
    uint32_t aw[8] = {a.x&0xFFFFu,a.x>>16,a.y&0xFFFFu,a.y>>16,
                      a.z&0xFFFFu,a.z>>16,a.w&0xFFFFu,a.w>>16};
    uint32_t bw[8] = {b.x&0xFFFFu,b.x>>16,b.y&0xFFFFu,b.y>>16,
                      b.z&0xFFFFu,b.z>>16,b.w&0xFFFFu,b.w>>16};
    uint32_t rowdt = 0;
    #pragma unroll
    for (int k=0;k<8;k++){ sa[k]+=aw[k]; sb[k]+=bw[k]; rowdt += aw[k]*bw[k]; }
    dt += (u64)rowdt;
  }
  #pragma unroll
  for (int k=0;k<8;k++)
    atomicAdd(&SAB[col+k], (u64)sa[k] | ((u64)sb[k]<<32));
  #pragma unroll
  for (int o=32;o>0;o>>=1) dt += __shfl_down(dt,o,64);
  if ((t&63)==0) atomicAdd(dotacc, dt);
}

extern "C" __global__ void __launch_bounds__(256)
final_atomic_kernel(const u64* __restrict__ SAB, const u64* __restrict__ dotacc,
                    const double* __restrict__ msepart, float* __restrict__ out)
{
  __shared__ double wpartd[4], wpartm[4];
  const int t = threadIdx.x;
  const double NMU = 4193792.0;
  double s = 0.0;
  for (int i=0;i<DCOL/256;i++){
    u64 v = SAB[i*256+t];
    s += ((double)(uint32_t)v - NMU)*((double)(uint32_t)(v>>32) - NMU);
  }
  double m = 0.0;
  for (int i=t;i<NROW;i+=256) m += msepart[i];
  #pragma unroll
  for (int o=32;o>0;o>>=1){ s+=__shfl_down(s,o,64); m+=__shfl_down(m,o,64); }
  int lane=t&63, wid=t>>6;
  if (lane==0){ wpartd[wid]=s; wpartm[wid]=m; }
  __syncthreads();
  if (t==0){
    double sasb   = wpartd[0]+wpartd[1]+wpartd[2]+wpartd[3];
    double msesum = wpartm[0]+wpartm[1]+wpartm[2]+wpartm[3];
    const double C     = 45812983808.0;
    const double NDMU2 = 140703130714112.0;
    double dot = (double)(*dotacc);
    double diag_sum = (dot - NDMU2) / C;
    double pos = diag_sum / (double)NROW;
    double stotal = sasb / C;
    double neg = (stotal - diag_sum) / ((double)NROW*(double)(NROW-1));
    double loss1 = msesum / ((double)NROW*(double)DCOL);
    out[0] = (float)(loss1 + 1.0 - pos + neg);
  }
}

extern "C" void kernel_launch(void* const* d_in, const int* in_sizes, int n_in,
                              void* d_out, int out_size, void* d_ws, size_t ws_size,
                              hipStream_t stream)
{
  const float* pred = (const float*)d_in[0];
  const float* eeg  = (const float*)d_in[1];
  float* out = (float*)d_out;

  char* ws = (char*)d_ws;
  const size_t OFF       = (size_t)2*NROW*DCOL*sizeof(uint16_t); // 32 MB ranks
  const size_t SZ_PART   = (size_t)64*DCOL*sizeof(u64);          // 4 MB
  const size_t NEED_PART = OFF + SZ_PART + DCOL*sizeof(u64) + 256*sizeof(u64)
                           + NROW*sizeof(double);
  const size_t NEED_ATOM = OFF + DCOL*sizeof(u64) + 8 + NROW*sizeof(double);

  if (ws_size >= NEED_PART){
    uint16_t* ranks  = (uint16_t*)ws;
    u64* SABpart     = (u64*)(ws + OFF);
    u64* SAB         = (u64*)(ws + OFF + SZ_PART);
    u64* dotpart     = (u64*)(ws + OFF + SZ_PART + DCOL*sizeof(u64));
    double* msepart  = (double*)(ws + OFF + SZ_PART + DCOL*sizeof(u64) + 256*sizeof(u64));

    rank_kernel<<<dim3(2*NROW), dim3(T1), 0, stream>>>(pred, eeg, ranks, msepart);
    colsum_part_kernel<<<dim3(4,64), dim3(256), 0, stream>>>(ranks, SABpart, dotpart);
    reduce_kernel<<<dim3(64), dim3(128), 0, stream>>>(SABpart, SAB);
    final_part_kernel<<<dim3(1), dim3(256), 0, stream>>>(SAB, dotpart, msepart, out);
  } else if (ws_size >= NEED_ATOM){
    uint16_t* ranks  = (uint16_t*)ws;
    u64* SAB         = (u64*)(ws + OFF);
    u64* dotacc      = (u64*)(ws + OFF + DCOL*sizeof(u64));
    double* msepart  = (double*)(ws + OFF + DCOL*sizeof(u64) + 8);

    hipMemsetAsync(ws + OFF, 0, DCOL*sizeof(u64) + 8, stream);
    rank_kernel<<<dim3(2*NROW), dim3(T1), 0, stream>>>(pred, eeg, ranks, msepart);
    colsum_atomic_kernel<<<dim3(4,64), dim3(256), 0, stream>>>(ranks, SAB, dotacc);
    final_atomic_kernel<<<dim3(1), dim3(256), 0, stream>>>(SAB, dotacc, msepart, out);
  } else {
    hipMemsetAsync(d_out, 0xFF, sizeof(float), stream);  // ws too small signal
  }
}

// Round 5
// 77.647 us; speedup vs baseline: 1.3936x; 1.0222x over previous
//
#include <hip/hip_runtime.h>
#include <stdint.h>

#define NROW 1024
#define DCOL 8192
#define T1   1024
#define EPT  8

typedef unsigned long long u64;

// order-preserving float -> uint32 transform
__device__ __forceinline__ uint32_t sortable_key(float f){
  uint32_t u = __float_as_uint(f);
  return u ^ ((uint32_t)((int32_t)u >> 31) | 0x80000000u);
}

// One block ranks one row. Two-level counting rank, all-integer, exact,
// deterministic. Grid pairing: blocks b and b+8 handle the same row pair
// (pred then eeg) -> same XCD slot (round-robin by bid%8), dispatched ~8
// apart, so the eeg block's pred-row re-read for MSE is L2-hot.
extern "C" __global__ void __launch_bounds__(T1)
rank_kernel(const float* __restrict__ pred, const float* __restrict__ eeg,
            uint16_t* __restrict__ ranks, double* __restrict__ msepart)
{
  __shared__ uint32_t h[DCOL];     // 32 KB
  __shared__ uint32_t g[DCOL];     // 32 KB
  __shared__ uint32_t wt[16];
  __shared__ double   redd[16];

  const int t = threadIdx.x;
  const int bid = blockIdx.x;
  const int pair = ((bid >> 4) << 3) | (bid & 7);   // [0,1024), twice each
  const bool is_eeg = (bid >> 3) & 1;
  const int lane = t & 63, wid = t >> 6;
  const float* src = is_eeg ? (eeg  + (size_t)pair * DCOL)
                            : (pred + (size_t)pair * DCOL);

  const float4* s4 = (const float4*)(src + t * EPT);
  float4 va = s4[0], vb = s4[1];

  // zero both LDS tables with b128 stores; overlaps with key/MSE computation
  {
    uint4 z = make_uint4(0u,0u,0u,0u);
    *(uint4*)&h[t*EPT]   = z;
    *(uint4*)&h[t*EPT+4] = z;
    *(uint4*)&g[t*EPT]   = z;
    *(uint4*)&g[t*EPT+4] = z;
  }

  double msum = 0.0;
  if (is_eeg){
    const float4* p4 = (const float4*)(pred + (size_t)pair * DCOL + t * EPT);
    float4 qa = p4[0], qb = p4[1];
    float d;
    d=qa.x-va.x; msum += (double)(d*d);
    d=qa.y-va.y; msum += (double)(d*d);
    d=qa.z-va.z; msum += (double)(d*d);
    d=qa.w-va.w; msum += (double)(d*d);
    d=qb.x-vb.x; msum += (double)(d*d);
    d=qb.y-vb.y; msum += (double)(d*d);
    d=qb.z-vb.z; msum += (double)(d*d);
    d=qb.w-vb.w; msum += (double)(d*d);
  }

  uint32_t key[EPT];
  key[0]=sortable_key(va.x); key[1]=sortable_key(va.y);
  key[2]=sortable_key(va.z); key[3]=sortable_key(va.w);
  key[4]=sortable_key(vb.x); key[5]=sortable_key(vb.y);
  key[6]=sortable_key(vb.z); key[7]=sortable_key(vb.w);
  __syncthreads();                               // (1) zeros visible

  // pass 1: histogram of top-13 bits
  #pragma unroll
  for (int j=0;j<EPT;j++) atomicAdd(&h[key[j]>>19], 1u);
  __syncthreads();                               // (2)

  // scan1: h[b] := (exclusive_prefix << 16) | count
  {
    uint4 ca = *(const uint4*)&h[t*EPT];
    uint4 cb = *(const uint4*)&h[t*EPT+4];
    uint32_t tot = ca.x+ca.y+ca.z+ca.w+cb.x+cb.y+cb.z+cb.w;
    uint32_t v = tot;
    #pragma unroll
    for (int o=1;o<64;o<<=1){ uint32_t u=__shfl_up(v,o,64); if(lane>=o) v+=u; }
    if (lane==63) wt[wid]=v;
    __syncthreads();                             // (3)
    // wave-uniform offset: sum of wt[w] for w<wid via 1 read + shfl reduce
    // (replaces a 16-iteration LDS broadcast-read loop)
    uint32_t x = (lane < wid) ? wt[lane] : 0u;
    #pragma unroll
    for (int o=32;o>0;o>>=1) x += __shfl_xor(x, o, 64);
    uint32_t run = x + v - tot;
    uint4 oa, ob;
    oa.x=(run<<16)|ca.x; run+=ca.x;
    oa.y=(run<<16)|ca.y; run+=ca.y;
    oa.z=(run<<16)|ca.z; run+=ca.z;
    oa.w=(run<<16)|ca.w; run+=ca.w;
    ob.x=(run<<16)|cb.x; run+=cb.x;
    ob.y=(run<<16)|cb.y; run+=cb.y;
    ob.z=(run<<16)|cb.z; run+=cb.z;
    ob.w=(run<<16)|cb.w; run+=cb.w;
    *(uint4*)&h[t*EPT]   = oa;
    *(uint4*)&h[t*EPT+4] = ob;
  }
  __syncthreads();                               // (4)

  // refine: b2 = p1 + lo19*cnt>>19 (monotone, disjoint per coarse bucket)
  // + pass-2 histogram directly into g
  uint32_t b2[EPT], e[EPT];
  #pragma unroll
  for (int j=0;j<EPT;j++){
    uint32_t hi = key[j]>>19, lo = key[j]&0x7FFFFu;
    uint32_t v  = h[hi];
    b2[j] = (v>>16) + (__umul24(lo, v&0xFFFFu)>>19);  // lo<2^19,cnt<=2^13
    e[j]  = (lo<<13) | (uint32_t)(t*EPT+j);
    atomicAdd(&g[b2[j]], 1u);
  }
  __syncthreads();                               // (5)

  // scan2: g[b] := (start<<16) | start   (low half doubles as scatter cursor)
  {
    uint4 ca = *(const uint4*)&g[t*EPT];
    uint4 cb = *(const uint4*)&g[t*EPT+4];
    uint32_t tot = ca.x+ca.y+ca.z+ca.w+cb.x+cb.y+cb.z+cb.w;
    uint32_t v = tot;
    #pragma unroll
    for (int o=1;o<64;o<<=1){ uint32_t u=__shfl_up(v,o,64); if(lane>=o) v+=u; }
    if (lane==63) wt[wid]=v;
    __syncthreads();                             // (6)
    uint32_t x = (lane < wid) ? wt[lane] : 0u;
    #pragma unroll
    for (int o=32;o>0;o>>=1) x += __shfl_xor(x, o, 64);
    uint32_t run = x + v - tot;
    uint4 oa, ob;
    oa.x=(run<<16)|run; run+=ca.x;
    oa.y=(run<<16)|run; run+=ca.y;
    oa.z=(run<<16)|run; run+=ca.z;
    oa.w=(run<<16)|run; run+=ca.w;
    ob.x=(run<<16)|run; run+=cb.x;
    ob.y=(run<<16)|run; run+=cb.y;
    ob.z=(run<<16)|run; run+=cb.z;
    ob.w=(run<<16)|run; run+=cb.w;
    *(uint4*)&g[t*EPT]   = oa;
    *(uint4*)&g[t*EPT+4] = ob;
  }
  __syncthreads();                               // (7)

  // scatter into h (h is dead after refine): one atomic yields start AND pos
  uint32_t old[EPT];
  #pragma unroll
  for (int j=0;j<EPT;j++){
    old[j] = atomicAdd(&g[b2[j]], 1u);           // hi16=start, lo16=pos cursor
    h[old[j] & 0xFFFFu] = e[j];
  }
  __syncthreads();                               // (8)

  // exact rank = start + #(smaller entries in refined bucket);
  // singleton buckets (37%, Poisson load 1) skip the peer loop entirely
  uint32_t rk[EPT];
  #pragma unroll
  for (int j=0;j<EPT;j++){
    uint32_t st = old[j] >> 16;
    uint32_t en = g[b2[j]] & 0xFFFFu;            // cursor now == bucket end
    uint32_t cnt = 0;
    if (en - st > 1){
      for (uint32_t p = st; p < en; ++p) cnt += (h[p] < e[j]) ? 1u : 0u;
    }
    rk[j] = st + cnt;
  }

  uint4 pk;
  pk.x = rk[0] | (rk[1]<<16);
  pk.y = rk[2] | (rk[3]<<16);
  pk.z = rk[4] | (rk[5]<<16);
  pk.w = rk[6] | (rk[7]<<16);
  const size_t orow = is_eeg ? (size_t)(NROW + pair) : (size_t)pair;
  *(uint4*)(ranks + orow*DCOL + (size_t)t*EPT) = pk;

  if (is_eeg){
    #pragma unroll
    for (int o=32;o>0;o>>=1) msum += __shfl_down(msum,o,64);
    if (lane==0) redd[wid]=msum;
    __syncthreads();
    if (t==0){
      double m=0.0;
      #pragma unroll
      for (int w=0;w<16;w++) m += redd[w];
      msepart[pair]=m;
    }
  }
}

// ---------- atomic-free back end ----------
// grid(8,64) x 128 threads: 1024 cols x 16 rows per block (2 blocks/CU).
extern "C" __global__ void __launch_bounds__(128)
colsum_part_kernel(const uint16_t* __restrict__ ranks,
                   u64* __restrict__ SABpart, u64* __restrict__ dotpart)
{
  __shared__ u64 redu[2];
  const int t = threadIdx.x;
  const int bx = blockIdx.x, by = blockIdx.y;
  const int col = bx*1024 + t*8;
  const int r0  = by*16;
  const uint16_t* rp = ranks;
  const uint16_t* re = ranks + (size_t)NROW*DCOL;
  uint32_t sa[8] = {0,0,0,0,0,0,0,0};
  uint32_t sb[8] = {0,0,0,0,0,0,0,0};
  u64 dt = 0ull;
  #pragma unroll
  for (int i=0;i<16;i++){
    uint4 a = *(const uint4*)&rp[(size_t)(r0+i)*DCOL + col];
    uint4 b = *(const uint4*)&re[(size_t)(r0+i)*DCOL + col];
    uint32_t aw[8] = {a.x&0xFFFFu,a.x>>16,a.y&0xFFFFu,a.y>>16,
                      a.z&0xFFFFu,a.z>>16,a.w&0xFFFFu,a.w>>16};
    uint32_t bw[8] = {b.x&0xFFFFu,b.x>>16,b.y&0xFFFFu,b.y>>16,
                      b.z&0xFFFFu,b.z>>16,b.w&0xFFFFu,b.w>>16};
    uint32_t rowdt = 0;
    #pragma unroll
    for (int k=0;k<8;k++){ sa[k]+=aw[k]; sb[k]+=bw[k]; rowdt += aw[k]*bw[k]; }
    dt += (u64)rowdt;                            // rowdt <= 8*8191^2 < 2^32
  }
  u64* dst = SABpart + (size_t)by*DCOL + col;    // sa<=16*8191 fits 16 bits+
  #pragma unroll
  for (int k=0;k<8;k++) dst[k] = (u64)sa[k] | ((u64)sb[k]<<32);

  #pragma unroll
  for (int o=32;o>0;o>>=1) dt += __shfl_down(dt,o,64);
  int lane=t&63, wid=t>>6;
  if (lane==0) redu[wid]=dt;
  __syncthreads();
  if (t==0) dotpart[by*8+bx] = redu[0]+redu[1];
}

// fold stripe partials AND the (SA-Nmu)(SB-Nmu) product: 64 doubles out
extern "C" __global__ void __launch_bounds__(128)
reduce2_kernel(const u64* __restrict__ SABpart, double* __restrict__ Spart)
{
  __shared__ double red[2];
  const int t = threadIdx.x;
  const int col = blockIdx.x*128 + t;
  u64 s = 0ull;
  #pragma unroll
  for (int by=0; by<64; by++) s += SABpart[(size_t)by*DCOL + col];
  const double NMU = 4193792.0;                  // N * mu, mu = (D-1)/2
  double d = ((double)(uint32_t)s - NMU) * ((double)(uint32_t)(s>>32) - NMU);
  #pragma unroll
  for (int o=32;o>0;o>>=1) d += __shfl_down(d,o,64);
  int lane=t&63, wid=t>>6;
  if (lane==0) red[wid]=d;
  __syncthreads();
  if (t==0) Spart[blockIdx.x] = red[0]+red[1];
}

extern "C" __global__ void __launch_bounds__(256)
final_kernel(const double* __restrict__ Spart, const u64* __restrict__ dotpart,
             const double* __restrict__ msepart, float* __restrict__ out)
{
  __shared__ double wpartd[4], wpartm[4];
  __shared__ u64 wpartu[4];
  const int t = threadIdx.x;
  double s = (t < 64) ? Spart[t] : 0.0;
  u64 d = dotpart[t] + dotpart[t+256];
  double m = 0.0;
  for (int i=t;i<NROW;i+=256) m += msepart[i];
  #pragma unroll
  for (int o=32;o>0;o>>=1){
    s+=__shfl_down(s,o,64); m+=__shfl_down(m,o,64); d+=__shfl_down(d,o,64);
  }
  int lane=t&63, wid=t>>6;
  if (lane==0){ wpartd[wid]=s; wpartm[wid]=m; wpartu[wid]=d; }
  __syncthreads();
  if (t==0){
    double sasb   = wpartd[0]+wpartd[1]+wpartd[2]+wpartd[3];
    double msesum = wpartm[0]+wpartm[1]+wpartm[2]+wpartm[3];
    double dot    = (double)(wpartu[0]+wpartu[1]+wpartu[2]+wpartu[3]);
    const double C     = 45812983808.0;          // D*(D^2-1)/12
    const double NDMU2 = 140703130714112.0;      // N * D * mu^2
    double diag_sum = (dot - NDMU2) / C;         // sum_i corr_ii
    double pos = diag_sum / (double)NROW;
    double stotal = sasb / C;                    // sum_ij corr_ij
    double neg = (stotal - diag_sum) / ((double)NROW*(double)(NROW-1));
    double loss1 = msesum / ((double)NROW*(double)DCOL);
    out[0] = (float)(loss1 + 1.0 - pos + neg);
  }
}

// ---------- atomic fallback (only if ws too small for partials) ----------
extern "C" __global__ void __launch_bounds__(256)
colsum_atomic_kernel(const uint16_t* __restrict__ ranks,
                     u64* __restrict__ SAB, u64* __restrict__ dotacc)
{
  const int t = threadIdx.x;
  const int col = blockIdx.x*2048 + t*8;
  const int r0  = blockIdx.y*16;
  const uint16_t* rp = ranks;
  const uint16_t* re = ranks + (size_t)NROW*DCOL;
  uint32_t sa[8] = {0,0,0,0,0,0,0,0};
  uint32_t sb[8] = {0,0,0,0,0,0,0,0};
  u64 dt = 0ull;
  for (int i=0;i<16;i++){
    uint4 a = *(const uint4*)&rp[(size_t)(r0+i)*DCOL + col];
    uint4 b = *(const uint4*)&re[(size_t)(r0+i)*DCOL + col];
    uint32_t aw[8] = {a.x&0xFFFFu,a.x>>16,a.y&0xFFFFu,a.y>>16,
                      a.z&0xFFFFu,a.z>>16,a.w&0xFFFFu,a.w>>16};
    uint32_t bw[8] = {b.x&0xFFFFu,b.x>>16,b.y&0xFFFFu,b.y>>16,
                      b.z&0xFFFFu,b.z>>16,b.w&0xFFFFu,b.w>>16};
    uint32_t rowdt = 0;
    #pragma unroll
    for (int k=0;k<8;k++){ sa[k]+=aw[k]; sb[k]+=bw[k]; rowdt += aw[k]*bw[k]; }
    dt += (u64)rowdt;
  }
  #pragma unroll
  for (int k=0;k<8;k++)
    atomicAdd(&SAB[col+k], (u64)sa[k] | ((u64)sb[k]<<32));
  #pragma unroll
  for (int o=32;o>0;o>>=1) dt += __shfl_down(dt,o,64);
  if ((t&63)==0) atomicAdd(dotacc, dt);
}

extern "C" __global__ void __launch_bounds__(256)
final_atomic_kernel(const u64* __restrict__ SAB, const u64* __restrict__ dotacc,
                    const double* __restrict__ msepart, float* __restrict__ out)
{
  __shared__ double wpartd[4], wpartm[4];
  const int t = threadIdx.x;
  const double NMU = 4193792.0;
  double s = 0.0;
  for (int i=0;i<DCOL/256;i++){
    u64 v = SAB[i*256+t];
    s += ((double)(uint32_t)v - NMU)*((double)(uint32_t)(v>>32) - NMU);
  }
  double m = 0.0;
  for (int i=t;i<NROW;i+=256) m += msepart[i];
  #pragma unroll
  for (int o=32;o>0;o>>=1){ s+=__shfl_down(s,o,64); m+=__shfl_down(m,o,64); }
  int lane=t&63, wid=t>>6;
  if (lane==0){ wpartd[wid]=s; wpartm[wid]=m; }
  __syncthreads();
  if (t==0){
    double sasb   = wpartd[0]+wpartd[1]+wpartd[2]+wpartd[3];
    double msesum = wpartm[0]+wpartm[1]+wpartm[2]+wpartm[3];
    const double C     = 45812983808.0;
    const double NDMU2 = 140703130714112.0;
    double dot = (double)(*dotacc);
    double diag_sum = (dot - NDMU2) / C;
    double pos = diag_sum / (double)NROW;
    double stotal = sasb / C;
    double neg = (stotal - diag_sum) / ((double)NROW*(double)(NROW-1));
    double loss1 = msesum / ((double)NROW*(double)DCOL);
    out[0] = (float)(loss1 + 1.0 - pos + neg);
  }
}

extern "C" void kernel_launch(void* const* d_in, const int* in_sizes, int n_in,
                              void* d_out, int out_size, void* d_ws, size_t ws_size,
                              hipStream_t stream)
{
  const float* pred = (const float*)d_in[0];
  const float* eeg  = (const float*)d_in[1];
  float* out = (float*)d_out;

  char* ws = (char*)d_ws;
  const size_t OFF       = (size_t)2*NROW*DCOL*sizeof(uint16_t); // 32 MB ranks
  const size_t SZ_PART   = (size_t)64*DCOL*sizeof(u64);          // 4 MB
  const size_t NEED_PART = OFF + SZ_PART + 64*sizeof(double) + 512*sizeof(u64)
                           + NROW*sizeof(double);
  const size_t NEED_ATOM = OFF + DCOL*sizeof(u64) + 8 + NROW*sizeof(double);

  if (ws_size >= NEED_PART){
    uint16_t* ranks  = (uint16_t*)ws;
    u64* SABpart     = (u64*)(ws + OFF);
    double* Spart    = (double*)(ws + OFF + SZ_PART);
    u64* dotpart     = (u64*)(ws + OFF + SZ_PART + 64*sizeof(double));
    double* msepart  = (double*)(ws + OFF + SZ_PART + 64*sizeof(double) + 512*sizeof(u64));

    rank_kernel<<<dim3(2*NROW), dim3(T1), 0, stream>>>(pred, eeg, ranks, msepart);
    colsum_part_kernel<<<dim3(8,64), dim3(128), 0, stream>>>(ranks, SABpart, dotpart);
    reduce2_kernel<<<dim3(64), dim3(128), 0, stream>>>(SABpart, Spart);
    final_kernel<<<dim3(1), dim3(256), 0, stream>>>(Spart, dotpart, msepart, out);
  } else if (ws_size >= NEED_ATOM){
    uint16_t* ranks  = (uint16_t*)ws;
    u64* SAB         = (u64*)(ws + OFF);
    u64* dotacc      = (u64*)(ws + OFF + DCOL*sizeof(u64));
    double* msepart  = (double*)(ws + OFF + DCOL*sizeof(u64) + 8);

    hipMemsetAsync(ws + OFF, 0, DCOL*sizeof(u64) + 8, stream);
    rank_kernel<<<dim3(2*NROW), dim3(T1), 0, stream>>>(pred, eeg, ranks, msepart);
    colsum_atomic_kernel<<<dim3(4,64), dim3(256), 0, stream>>>(ranks, SAB, dotacc);
    final_atomic_kernel<<<dim3(1), dim3(256), 0, stream>>>(SAB, dotacc, msepart, out);
  } else {
    hipMemsetAsync(d_out, 0xFF, sizeof(float), stream);  // ws too small signal
  }
}